// Round 3
// baseline (8010.421 us; speedup 1.0000x reference)
//
#include <hip/hip_runtime.h>
#include <hip/hip_bf16.h>

#define BB 4096
#define INF 8192
#define SS 128
#define HH 256

typedef __attribute__((ext_vector_type(8))) short short8;
typedef __attribute__((ext_vector_type(4))) float f32x4;

__device__ __forceinline__ float sigm(float x) { return 1.f / (1.f + __expf(-x)); }
__device__ __forceinline__ float tanh_fast(float x) {
    float cx = fminf(15.f, fmaxf(-15.f, x));
    float e = __expf(2.f * cx);
    return (e - 1.f) / (e + 1.f);
}
__device__ __forceinline__ unsigned short f2bf(float f) {
    __hip_bfloat16 b = __float2bfloat16(f);
    return *(unsigned short*)&b;
}
__device__ __forceinline__ float bf2f(unsigned short u) {
    __hip_bfloat16 b = *(__hip_bfloat16*)&u;
    return __bfloat162float(b);
}

#define GLD(g, l) __builtin_amdgcn_global_load_lds(                              \
        (const __attribute__((address_space(1))) void*)(g),                      \
        (__attribute__((address_space(3))) void*)(l), 16, 0, 0)

// ---- BatchNorm stats ------------------------------------------------------
__global__ __launch_bounds__(256) void bn_partial(const float* __restrict__ x,
                                                  float* __restrict__ colsum,
                                                  float* __restrict__ colsumsq) {
    int j = blockIdx.x * 256 + threadIdx.x;
    int r0 = blockIdx.y * 256;
    float s1 = 0.f, s2 = 0.f;
    for (int r = r0; r < r0 + 256; ++r) {
        float v = x[(size_t)r * INF + j];
        s1 += v;
        s2 += v * v;
    }
    atomicAdd(&colsum[j], s1);
    atomicAdd(&colsumsq[j], s2);
}

__global__ __launch_bounds__(256) void bn_finalize(const float* __restrict__ colsum,
                                                   const float* __restrict__ colsumsq,
                                                   const float* __restrict__ gamma,
                                                   const float* __restrict__ beta,
                                                   float* __restrict__ scl,
                                                   float* __restrict__ shf) {
    int j = blockIdx.x * 256 + threadIdx.x;
    float mean = colsum[j] * (1.f / BB);
    float var = colsumsq[j] * (1.f / BB) - mean * mean;
    float a = gamma[j] * rsqrtf(var + 1e-5f);
    scl[j] = a;
    shf[j] = beta[j] - mean * a;
}

// ---- split fp32 -> bf16 hi/lo with BN affine fused ------------------------
__global__ __launch_bounds__(256) void split_x(const float* __restrict__ x,
                                               const float* __restrict__ scl,
                                               const float* __restrict__ shf,
                                               unsigned short* __restrict__ hi,
                                               unsigned short* __restrict__ lo) {
    size_t i = ((size_t)blockIdx.x * 256 + threadIdx.x) * 4;
    float4 v = *(const float4*)(x + i);
    int col = (int)(i & (INF - 1));
    float4 s = *(const float4*)(scl + col);
    float4 h = *(const float4*)(shf + col);
    float f[4] = {fmaf(v.x, s.x, h.x), fmaf(v.y, s.y, h.y),
                  fmaf(v.z, s.z, h.z), fmaf(v.w, s.w, h.w)};
    ushort4 hv, lv;
    unsigned short* hp = (unsigned short*)&hv;
    unsigned short* lp = (unsigned short*)&lv;
#pragma unroll
    for (int k = 0; k < 4; ++k) {
        unsigned short hb = f2bf(f[k]);
        hp[k] = hb;
        lp[k] = f2bf(f[k] - bf2f(hb));
    }
    *(ushort4*)(hi + i) = hv;
    *(ushort4*)(lo + i) = lv;
}

__global__ __launch_bounds__(256) void split_w(const float* __restrict__ w,
                                               unsigned short* __restrict__ hi,
                                               unsigned short* __restrict__ lo) {
    size_t i = ((size_t)blockIdx.x * 256 + threadIdx.x) * 4;
    float4 v = *(const float4*)(w + i);
    float f[4] = {v.x, v.y, v.z, v.w};
    ushort4 hv, lv;
    unsigned short* hp = (unsigned short*)&hv;
    unsigned short* lp = (unsigned short*)&lv;
#pragma unroll
    for (int k = 0; k < 4; ++k) {
        unsigned short hb = f2bf(f[k]);
        hp[k] = hb;
        lp[k] = f2bf(f[k] - bf2f(hb));
    }
    *(ushort4*)(hi + i) = hv;
    *(ushort4*)(lo + i) = lv;
}

// ---- pack W_ih|W_hh into gate-interleaved rows + split --------------------
// Wcat row r (r=4*hcol+gate): cols 0..63 = W_ih[gate*256+hcol], 64..319 = W_hh row.
__global__ __launch_bounds__(128) void pack_w(const float* __restrict__ Wih,
                                              const float* __restrict__ Whh,
                                              const float* __restrict__ bih,
                                              const float* __restrict__ bhh,
                                              unsigned short* __restrict__ Wch,
                                              unsigned short* __restrict__ Wcl,
                                              float* __restrict__ biascat) {
    int r = blockIdx.x;  // 0..1023
    int c = r >> 2, g = r & 3;
    int t = threadIdx.x;
    if (t == 0) biascat[r] = bih[g * 256 + c] + bhh[g * 256 + c];
    if (t >= 80) return;
    float4 v;
    if (t < 16)
        v = *(const float4*)(Wih + (size_t)(g * 256 + c) * 64 + t * 4);
    else
        v = *(const float4*)(Whh + (size_t)(g * 256 + c) * 256 + (t - 16) * 4);
    float f[4] = {v.x, v.y, v.z, v.w};
    ushort4 hv, lv;
    unsigned short* hp = (unsigned short*)&hv;
    unsigned short* lp = (unsigned short*)&lv;
#pragma unroll
    for (int k = 0; k < 4; ++k) {
        unsigned short hb = f2bf(f[k]);
        hp[k] = hb;
        lp[k] = f2bf(f[k] - bf2f(hb));
    }
    *(ushort4*)(Wch + (size_t)r * 320 + t * 4) = hv;
    *(ushort4*)(Wcl + (size_t)r * 320 + t * 4) = lv;
}

// ---- big GEMM: proj = xn @ W_in^T, split-bf16 MFMA (proven 1810us version)
__global__ __launch_bounds__(256) void gemm_mfma_split(
    const unsigned short* __restrict__ Ah, const unsigned short* __restrict__ Al,
    const unsigned short* __restrict__ Bh, const unsigned short* __restrict__ Bl,
    unsigned short* __restrict__ projsplit, int K) {
    __shared__ unsigned short AsH[4096], AsL[4096], BsH[4096], BsL[4096];
    const int tid = threadIdx.x;
    const int lane = tid & 63, wid = tid >> 6;
    int bid = blockIdx.x;
    int grp = bid >> 8, loc = bid & 255;
    int bx = ((grp & 3) << 4) | (loc & 15);
    int by = ((grp >> 2) << 4) | (loc >> 4);
    const int row0 = by << 7, col0 = bx << 7;
    const int wm = (wid & 1) << 6, wn = (wid >> 1) << 6;
    const int q = lane >> 4, l15 = lane & 15;

    const int s0 = wid * 128 + lane, s1 = s0 + 64;
    const int r0 = s0 >> 2, k0 = (((s0 & 3) ^ ((r0 >> 1) & 3)) << 3);
    const int r1 = s1 >> 2, k1 = (((s1 & 3) ^ ((r1 >> 1) & 3)) << 3);
    const size_t aoff0 = (size_t)(row0 + r0) * K + k0;
    const size_t aoff1 = (size_t)(row0 + r1) * K + k1;
    const size_t boff0 = (size_t)(col0 + r0) * K + k0;
    const size_t boff1 = (size_t)(col0 + r1) * K + k1;
    const int lb0 = (wid * 128) * 8, lb1 = lb0 + 512;

    f32x4 acc[4][4];
#pragma unroll
    for (int i = 0; i < 4; ++i)
#pragma unroll
        for (int j = 0; j < 4; ++j) acc[i][j] = (f32x4){0.f, 0.f, 0.f, 0.f};

    for (int kb = 0; kb < K; kb += 32) {
        __syncthreads();
        GLD(Ah + aoff0 + kb, &AsH[lb0]);
        GLD(Ah + aoff1 + kb, &AsH[lb1]);
        GLD(Al + aoff0 + kb, &AsL[lb0]);
        GLD(Al + aoff1 + kb, &AsL[lb1]);
        GLD(Bh + boff0 + kb, &BsH[lb0]);
        GLD(Bh + boff1 + kb, &BsH[lb1]);
        GLD(Bl + boff0 + kb, &BsL[lb0]);
        GLD(Bl + boff1 + kb, &BsL[lb1]);
        __syncthreads();

        short8 ahf[4], alf[4], bhf[4], blf[4];
#pragma unroll
        for (int i = 0; i < 4; ++i) {
            int ra = wm + i * 16 + l15;
            int offa = ra * 32 + ((q ^ ((ra >> 1) & 3)) << 3);
            ahf[i] = *(const short8*)&AsH[offa];
            alf[i] = *(const short8*)&AsL[offa];
            int rb = wn + i * 16 + l15;
            int offb = rb * 32 + ((q ^ ((rb >> 1) & 3)) << 3);
            bhf[i] = *(const short8*)&BsH[offb];
            blf[i] = *(const short8*)&BsL[offb];
        }
#pragma unroll
        for (int i = 0; i < 4; ++i)
#pragma unroll
            for (int j = 0; j < 4; ++j) {
                acc[i][j] = __builtin_amdgcn_mfma_f32_16x16x32_bf16(ahf[i], bhf[j], acc[i][j], 0, 0, 0);
                acc[i][j] = __builtin_amdgcn_mfma_f32_16x16x32_bf16(ahf[i], blf[j], acc[i][j], 0, 0, 0);
                acc[i][j] = __builtin_amdgcn_mfma_f32_16x16x32_bf16(alf[i], bhf[j], acc[i][j], 0, 0, 0);
            }
    }

#pragma unroll
    for (int i = 0; i < 4; ++i)
#pragma unroll
        for (int j = 0; j < 4; ++j) {
            int col = col0 + wn + j * 16 + l15;
            int slice = col >> 6, c6 = col & 63;
            unsigned short* ps = projsplit + (size_t)slice * 524288;
#pragma unroll
            for (int r = 0; r < 4; ++r) {
                int row = row0 + wm + i * 16 + q * 4 + r;
                float v = acc[i][j][r];
                unsigned short hb = f2bf(v);
                ps[row * 64 + c6] = hb;
                ps[262144 + row * 64 + c6] = f2bf(v - bf2f(hb));
            }
        }
}

// ---- persistent LSTM: all 128 steps in one regular launch -----------------
// 256 blocks x 256 threads, 1 block/CU (151KiB LDS forces it, grid==CU count
// so all blocks co-resident). Block (rt,ct): rows rt*256..+256, hidden cols
// ct*16..+16 (gate rows ct*64..+64). Cross-step h dependency is PANEL-LOCAL:
// block (rt,ct) only reads h rows of panel rt, written by the 16 blocks with
// the same rt. Software barrier: per-panel monotonic counter + agent-scope
// fences (correct regardless of XCD placement). Counter zeroed by memset
// each launch, so graph replays are safe. W persistent in LDS (XOR swizzle);
// A direct global->VGPR depth-2 prefetch; c-state in registers.
__global__ __launch_bounds__(256, 1) void lstm_seq(
    const unsigned short* __restrict__ projsplit,
    const unsigned short* __restrict__ Wch, const unsigned short* __restrict__ Wcl,
    const float* __restrict__ biascat,
    unsigned short* __restrict__ h0h, unsigned short* __restrict__ h0l,
    unsigned short* __restrict__ h1h, unsigned short* __restrict__ h1l,
    float* __restrict__ hs, int* __restrict__ bar) {
    __shared__ unsigned short BsH[20480];   // 64 gate-rows x 320 K (40 KiB)
    __shared__ unsigned short BsL[20480];   // 40 KiB
    __shared__ float gates[256 * 68];       // 68 KiB
    __shared__ float sbias[64];

    const int tid = threadIdx.x;
    const int lane = tid & 63, w = tid >> 6;
    const int l15 = lane & 15, q = lane >> 4, qk = q * 8;
    const int bid = blockIdx.x;
    const int rt = bid & 15, ct = bid >> 4;
    int* cnt = bar + rt * 32;  // 128B-separated per-panel counters

    // ---- preload W into swizzled LDS (once) ----
    for (int it = 0; it < 10; ++it) {
        int idx = it * 256 + tid;          // 0..2559 = 64 rows x 40 slots
        int gg = idx / 40, sl0 = idx - gg * 40;
        int sl = (sl0 & 0x38) | ((sl0 ^ gg) & 7);
        *(short8*)((char*)BsH + gg * 640 + sl * 16) =
            *(const short8*)(Wch + (size_t)(ct * 64 + gg) * 320 + sl0 * 8);
        *(short8*)((char*)BsL + gg * 640 + sl * 16) =
            *(const short8*)(Wcl + (size_t)(ct * 64 + gg) * 320 + sl0 * 8);
    }
    if (tid < 64) sbias[tid] = biascat[ct * 64 + tid];
    __syncthreads();

    const int grow = rt * 256 + w * 64 + l15;  // + i*16 per fragment
    const int hc = tid & 15, rg4 = tid >> 4;   // cell-update mapping
    float c[16];
#pragma unroll
    for (int i = 0; i < 16; ++i) c[i] = 0.f;

#define LOADA(buf, kb_)                                                          \
    do {                                                                         \
        _Pragma("unroll") for (int i_ = 0; i_ < 4; ++i_) {                       \
            if ((kb_) < 2) {                                                     \
                size_t o = (size_t)(grow + i_ * 16) * 64 + (kb_) * 32 + qk;      \
                aH[buf][i_] = *(const short8*)(psh + o);                         \
                aL[buf][i_] = *(const short8*)(psl2 + o);                        \
            } else {                                                             \
                size_t o = (size_t)(grow + i_ * 16) * 256 + ((kb_) * 32 - 64) + qk; \
                aH[buf][i_] = *(const short8*)(hih + o);                         \
                aL[buf][i_] = *(const short8*)(hil + o);                         \
            }                                                                    \
        }                                                                        \
    } while (0)
#define LOADB(buf, kb_)                                                          \
    do {                                                                         \
        _Pragma("unroll") for (int j_ = 0; j_ < 4; ++j_) {                       \
            int gg = j_ * 16 + l15;                                              \
            int slot = (kb_) * 4 + q;                                            \
            int sl = (slot & 0x38) | ((slot ^ gg) & 7);                          \
            int off = gg * 640 + sl * 16;                                        \
            bH[buf][j_] = *(const short8*)((const char*)BsH + off);              \
            bL[buf][j_] = *(const short8*)((const char*)BsL + off);              \
        }                                                                        \
    } while (0)

    for (int s = 0; s < 128; ++s) {
        const unsigned short* psh = projsplit + (size_t)s * 524288;
        const unsigned short* psl2 = psh + 262144;
        const unsigned short* hih = (s & 1) ? h1h : h0h;
        const unsigned short* hil = (s & 1) ? h1l : h0l;
        unsigned short* hoh = (s & 1) ? h0h : h1h;
        unsigned short* hol = (s & 1) ? h0l : h1l;

        f32x4 acc[4][4];
#pragma unroll
        for (int i = 0; i < 4; ++i)
#pragma unroll
            for (int j = 0; j < 4; ++j) acc[i][j] = (f32x4){0.f, 0.f, 0.f, 0.f};

        short8 aH[2][4], aL[2][4], bH[2][4], bL[2][4];
        LOADA(0, 0);
        LOADA(1, 1);
        LOADB(0, 0);
#pragma unroll
        for (int kb = 0; kb < 10; ++kb) {
            const int cb = kb & 1, nb = cb ^ 1;
            if (kb < 9) LOADB(nb, kb + 1);
#pragma unroll
            for (int i = 0; i < 4; ++i)
#pragma unroll
                for (int j = 0; j < 4; ++j) {
                    acc[i][j] = __builtin_amdgcn_mfma_f32_16x16x32_bf16(aH[cb][i], bH[cb][j], acc[i][j], 0, 0, 0);
                    acc[i][j] = __builtin_amdgcn_mfma_f32_16x16x32_bf16(aH[cb][i], bL[cb][j], acc[i][j], 0, 0, 0);
                    acc[i][j] = __builtin_amdgcn_mfma_f32_16x16x32_bf16(aL[cb][i], bH[cb][j], acc[i][j], 0, 0, 0);
                }
            if (kb < 8) LOADA(cb, kb + 2);
        }

        // gates -> LDS (row = w*64+i*16+q*4+r, col = j*16+l15)
#pragma unroll
        for (int i = 0; i < 4; ++i)
#pragma unroll
            for (int j = 0; j < 4; ++j)
#pragma unroll
                for (int r = 0; r < 4; ++r)
                    gates[(w * 64 + i * 16 + q * 4 + r) * 68 + j * 16 + l15] = acc[i][j][r];
        __syncthreads();

        // fused cell update: thread -> hidden col hc, 16 rows
#pragma unroll
        for (int rr = 0; rr < 16; ++rr) {
            int row = rg4 * 16 + rr;
            float4 g4 = *(const float4*)&gates[row * 68 + 4 * hc];
            float4 b4 = *(const float4*)&sbias[4 * hc];
            float i_ = sigm(g4.x + b4.x);
            float f_ = sigm(g4.y + b4.y);
            float g_ = tanh_fast(g4.z + b4.z);
            float o_ = sigm(g4.w + b4.w);
            float cn = fmaf(f_, c[rr], i_ * g_);
            c[rr] = cn;
            float hn = o_ * tanh_fast(cn);
            size_t ci = (size_t)(rt * 256 + row) * HH + ct * 16 + hc;
            hs[(size_t)s * (BB * HH) + ci] = hn;
            unsigned short hb = f2bf(hn);
            hoh[ci] = hb;
            hol[ci] = f2bf(hn - bf2f(hb));
        }

        // panel barrier: wait for the 16 blocks sharing this row panel.
        // __syncthreads drains all the block's stores (vmcnt(0) before
        // s_barrier); release fence + device atomic publishes them; acquire
        // fence invalidates stale cached h before next step's reads.
        __syncthreads();
        if (s < 127) {
            if (tid == 0) {
                __threadfence();
                __hip_atomic_fetch_add(cnt, 1, __ATOMIC_RELEASE,
                                       __HIP_MEMORY_SCOPE_AGENT);
                int target = 16 * (s + 1);
                while (__hip_atomic_load(cnt, __ATOMIC_ACQUIRE,
                                         __HIP_MEMORY_SCOPE_AGENT) < target) {}
                __threadfence();
            }
            __syncthreads();
        }
    }
#undef LOADA
#undef LOADB
}

// ---- q[b,s] = hs[s,b,:] . W_out ------------------------------------------
__global__ __launch_bounds__(256) void q_kernel(const float* __restrict__ hs,
                                                const float* __restrict__ wout,
                                                float* __restrict__ q) {
    int wid = threadIdx.x >> 6, lane = threadIdx.x & 63;
    int p = (blockIdx.x << 2) + wid;
    int b = p & (BB - 1), s = p >> 12;
    const float* hp = hs + ((size_t)s * BB + b) * HH + (lane << 2);
    float4 h4 = *(const float4*)hp;
    float4 w4 = *(const float4*)(wout + (lane << 2));
    float v = h4.x * w4.x + h4.y * w4.y + h4.z * w4.z + h4.w * w4.w;
#pragma unroll
    for (int off = 32; off; off >>= 1) v += __shfl_xor(v, off);
    if (lane == 0) q[b * SS + s] = v;
}

// ---- attention logits, split-K (8 chunks of K=4096) ----------------------
__global__ __launch_bounds__(256) void attn_part(const float* __restrict__ hs,
                                                 const float* __restrict__ Wta,
                                                 float* __restrict__ part) {
    __shared__ float As[16][68];
    __shared__ float Bs[16][132];
    const int tid = threadIdx.x;
    const int tx = tid & 15, ty = tid >> 4;
    const int row0 = blockIdx.x << 6;
    const int jc = blockIdx.y;
    const int lrA = tid >> 2, lkA = (tid & 3) << 2;
    const int lrB = tid >> 1, lkB = (tid & 1) << 3;

    float acc[4][8];
#pragma unroll
    for (int i = 0; i < 4; ++i)
#pragma unroll
        for (int j = 0; j < 8; ++j) acc[i][j] = 0.f;

    for (int kb = 0; kb < 256; ++kb) {
        int k0 = (jc << 12) + (kb << 4);
        int sidx = k0 >> 8, h0 = k0 & 255;
        float4 av = *(const float4*)(hs + ((size_t)sidx * BB + row0 + lrA) * HH + h0 + lkA);
        const float* wp = Wta + (size_t)lrB * (SS * HH) + k0 + lkB;
        float4 bv0 = *(const float4*)wp;
        float4 bv1 = *(const float4*)(wp + 4);
        __syncthreads();
        As[lkA + 0][lrA] = av.x;
        As[lkA + 1][lrA] = av.y;
        As[lkA + 2][lrA] = av.z;
        As[lkA + 3][lrA] = av.w;
        Bs[lkB + 0][lrB] = bv0.x;
        Bs[lkB + 1][lrB] = bv0.y;
        Bs[lkB + 2][lrB] = bv0.z;
        Bs[lkB + 3][lrB] = bv0.w;
        Bs[lkB + 4][lrB] = bv1.x;
        Bs[lkB + 5][lrB] = bv1.y;
        Bs[lkB + 6][lrB] = bv1.z;
        Bs[lkB + 7][lrB] = bv1.w;
        __syncthreads();
#pragma unroll
        for (int k = 0; k < 16; ++k) {
            float4 af = *(const float4*)&As[k][ty << 2];
            float4 b0 = *(const float4*)&Bs[k][tx << 2];
            float4 b1 = *(const float4*)&Bs[k][64 + (tx << 2)];
            float ar[4] = {af.x, af.y, af.z, af.w};
            float br[8] = {b0.x, b0.y, b0.z, b0.w, b1.x, b1.y, b1.z, b1.w};
#pragma unroll
            for (int i = 0; i < 4; ++i)
#pragma unroll
                for (int j = 0; j < 8; ++j)
                    acc[i][j] = fmaf(ar[i], br[j], acc[i][j]);
        }
    }
#pragma unroll
    for (int i = 0; i < 4; ++i) {
        int b = row0 + (ty << 2) + i;
        float* pp = part + ((size_t)jc * BB + b) * SS;
        float4 o0 = {acc[i][0], acc[i][1], acc[i][2], acc[i][3]};
        float4 o1 = {acc[i][4], acc[i][5], acc[i][6], acc[i][7]};
        *(float4*)(pp + (tx << 2)) = o0;
        *(float4*)(pp + 64 + (tx << 2)) = o1;
    }
}

// ---- relu -> softmax -> weighted sum of q --------------------------------
__global__ __launch_bounds__(256) void attn_finalize(const float* __restrict__ part,
                                                     const float* __restrict__ b_ta,
                                                     const float* __restrict__ q,
                                                     float* __restrict__ out) {
    int wid = threadIdx.x >> 6, lane = threadIdx.x & 63;
    int b = (blockIdx.x << 2) + wid;
    float l0 = b_ta[lane], l1 = b_ta[lane + 64];
#pragma unroll
    for (int j = 0; j < 8; ++j) {
        const float* pp = part + ((size_t)j * BB + b) * SS;
        l0 += pp[lane];
        l1 += pp[lane + 64];
    }
    l0 = fmaxf(l0, 0.f);
    l1 = fmaxf(l1, 0.f);
    float mx = fmaxf(l0, l1);
#pragma unroll
    for (int off = 32; off; off >>= 1) mx = fmaxf(mx, __shfl_xor(mx, off));
    float e0 = __expf(l0 - mx), e1 = __expf(l1 - mx);
    float num = fmaf(e0, q[b * SS + lane], e1 * q[b * SS + lane + 64]);
    float den = e0 + e1;
#pragma unroll
    for (int off = 32; off; off >>= 1) {
        num += __shfl_xor(num, off);
        den += __shfl_xor(den, off);
    }
    if (lane == 0) out[b] = num / den;
}

extern "C" void kernel_launch(void* const* d_in, const int* in_sizes, int n_in,
                              void* d_out, int out_size, void* d_ws, size_t ws_size,
                              hipStream_t stream) {
    const float* x     = (const float*)d_in[0];
    const float* gamma = (const float*)d_in[1];
    const float* beta_ = (const float*)d_in[2];
    const float* W_in  = (const float*)d_in[3];
    const float* W_ih  = (const float*)d_in[4];
    const float* b_ih  = (const float*)d_in[5];
    const float* W_hh  = (const float*)d_in[6];
    const float* b_hh  = (const float*)d_in[7];
    const float* W_ta  = (const float*)d_in[8];
    const float* b_ta  = (const float*)d_in[9];
    const float* W_out = (const float*)d_in[10];
    float* out = (float*)d_out;

    float* ws = (float*)d_ws;
    // --- small region (float offsets) ---
    float* colsum   = ws;                 // 8192
    float* colsumsq = ws + 8192;          // 8192
    float* scl      = ws + 16384;         // 8192
    float* shf      = ws + 24576;         // 8192
    float* biascat  = ws + 32768;         // 1024
    float* qbuf     = ws + 33792;         // 524288
    float* part     = ws + 558080;        // 8*4096*128 = 4194304
    int*   bar      = (int*)(ws + 4752384);  // 16*32 ints (old cbuf slot)
    unsigned short* Wch   = (unsigned short*)(ws + 5800960);  // 327680 us
    unsigned short* Wcl   = (unsigned short*)(ws + 5964800);  // 327680 us
    unsigned short* hsp0h = (unsigned short*)(ws + 6128640);  // 1048576 us
    unsigned short* hsp0l = (unsigned short*)(ws + 6652928);
    unsigned short* hsp1h = (unsigned short*)(ws + 7177216);
    unsigned short* hsp1l = (unsigned short*)(ws + 7701504);  // ends 8225792
    // --- hs region (537 MB) + aliased transients ---
    float* hs = ws + 8388608;             // 128*4096*256 floats
    unsigned short* xh = (unsigned short*)hs;        // phase-1 aliases
    unsigned short* xl = xh + 33554432;
    unsigned short* Wh = xl + 33554432;
    unsigned short* Wl = Wh + 67108864;
    unsigned short* projsplit = (unsigned short*)(ws + 8388608 + 108003328);

    hipMemsetAsync(colsum, 0, 2 * 8192 * sizeof(float), stream);
    hipMemsetAsync(hsp0h, 0, 4194304, stream);  // hsp0h+hsp0l (h at s=0 is 0)
    hipMemsetAsync(bar, 0, 16 * 32 * sizeof(int), stream);  // panel barriers

    bn_partial<<<dim3(32, 16), 256, 0, stream>>>(x, colsum, colsumsq);
    bn_finalize<<<32, 256, 0, stream>>>(colsum, colsumsq, gamma, beta_, scl, shf);
    split_x<<<32768, 256, 0, stream>>>(x, scl, shf, xh, xl);
    split_w<<<65536, 256, 0, stream>>>(W_in, Wh, Wl);
    pack_w<<<1024, 128, 0, stream>>>(W_ih, W_hh, b_ih, b_hh, Wch, Wcl, biascat);
    gemm_mfma_split<<<2048, 256, 0, stream>>>(xh, xl, Wh, Wl, projsplit, INF);
    lstm_seq<<<256, 256, 0, stream>>>(projsplit, Wch, Wcl, biascat,
                                      hsp0h, hsp0l, hsp1h, hsp1l, hs, bar);
    q_kernel<<<131072, 256, 0, stream>>>(hs, W_out, qbuf);
    attn_part<<<dim3(64, 8), 256, 0, stream>>>(hs, W_ta, part);
    attn_finalize<<<1024, 256, 0, stream>>>(part, b_ta, qbuf, out);
}